// Round 7
// baseline (23817.764 us; speedup 1.0000x reference)
//
#include <hip/hip_runtime.h>
#include <math.h>

#define S_LEN 4096
#define HDIRC 256
#define NTAG 10
#define START_TAG 8
#define STOP_TAG 9
#define NEGV -10000.0f

// -------- workspace layout (float units) --------
#define XW_OFF 0UL
#define XW_SZ  (2UL * S_LEN * 1024)          // xw[dir][t][1024]
#define HS_OFF (XW_OFF + XW_SZ)
#define HS_SZ  (2UL * S_LEN * 256)           // hs[dir][t][256] (dir1 indexed by backward step)
#define WT_OFF (HS_OFF + HS_SZ)
#define WT_SZ  (2UL * 256 * 1024)            // WihT[dir][k][r]
#define FE_OFF (WT_OFF + WT_SZ)
#define FE_SZ  ((size_t)S_LEN * NTAG)        // feats[t][tag]
#define RING_OFF (FE_OFF + FE_SZ)            // even float offset -> 8B aligned
#define RING_SZ (2UL * 2 * 256 * 2)          // u64 ring[dir][slot][dim], as floats

// ---------------- Wih transpose: [1024][256] -> [256][1024] ----------------
__global__ void transpose_wih(const float* __restrict__ wf,
                              const float* __restrict__ wb,
                              float* __restrict__ wT) {
    __shared__ float tile[32][33];
    const float* src = blockIdx.z ? wb : wf;
    float* dst = wT + (size_t)blockIdx.z * 256 * 1024;
    int x = blockIdx.x * 32 + threadIdx.x;   // k  (0..255)
    int y = blockIdx.y * 32 + threadIdx.y;   // r  (0..1023)
    tile[threadIdx.y][threadIdx.x] = src[y * 256 + x];
    __syncthreads();
    int ko = blockIdx.x * 32 + threadIdx.y;
    int ro = blockIdx.y * 32 + threadIdx.x;
    dst[(size_t)ko * 1024 + ro] = tile[threadIdx.x][threadIdx.y];
}

// ---------------- xW = emb[sent] @ Wih^T + (bih+bhh) ----------------
__global__ __launch_bounds__(256) void xw_gemm(
    const int* __restrict__ sent, const float* __restrict__ emb,
    const float* __restrict__ wT,
    const float* __restrict__ bih_f, const float* __restrict__ bhh_f,
    const float* __restrict__ bih_b, const float* __restrict__ bhh_b,
    float* __restrict__ xw) {
    int dir = blockIdx.y;
    int t0 = blockIdx.x * 8;
    int tid = threadIdx.x;
    __shared__ __align__(16) float xs[8][256];
    for (int i = 0; i < 8; ++i) {
        int t = t0 + i;
        int pos = dir ? (S_LEN - 1 - t) : t;
        int idx = sent[pos];
        xs[i][tid] = emb[(size_t)idx * 256 + tid];
    }
    __syncthreads();
    const float* w = wT + (size_t)dir * 256 * 1024;
    const float* bi = dir ? bih_b : bih_f;
    const float* bh = dir ? bhh_b : bhh_f;
    float4 bv;
    bv.x = bi[4 * tid + 0] + bh[4 * tid + 0];
    bv.y = bi[4 * tid + 1] + bh[4 * tid + 1];
    bv.z = bi[4 * tid + 2] + bh[4 * tid + 2];
    bv.w = bi[4 * tid + 3] + bh[4 * tid + 3];
    float4 acc[8];
#pragma unroll
    for (int i = 0; i < 8; ++i) acc[i] = bv;
    for (int k4 = 0; k4 < 64; ++k4) {
        float4 w0 = ((const float4*)(w + (size_t)(4 * k4 + 0) * 1024))[tid];
        float4 w1 = ((const float4*)(w + (size_t)(4 * k4 + 1) * 1024))[tid];
        float4 w2 = ((const float4*)(w + (size_t)(4 * k4 + 2) * 1024))[tid];
        float4 w3 = ((const float4*)(w + (size_t)(4 * k4 + 3) * 1024))[tid];
#pragma unroll
        for (int i = 0; i < 8; ++i) {
            float4 xv = *(const float4*)&xs[i][4 * k4];
            acc[i].x = fmaf(w0.x, xv.x, acc[i].x);
            acc[i].y = fmaf(w0.y, xv.x, acc[i].y);
            acc[i].z = fmaf(w0.z, xv.x, acc[i].z);
            acc[i].w = fmaf(w0.w, xv.x, acc[i].w);
            acc[i].x = fmaf(w1.x, xv.y, acc[i].x);
            acc[i].y = fmaf(w1.y, xv.y, acc[i].y);
            acc[i].z = fmaf(w1.z, xv.y, acc[i].z);
            acc[i].w = fmaf(w1.w, xv.y, acc[i].w);
            acc[i].x = fmaf(w2.x, xv.z, acc[i].x);
            acc[i].y = fmaf(w2.y, xv.z, acc[i].y);
            acc[i].z = fmaf(w2.z, xv.z, acc[i].z);
            acc[i].w = fmaf(w2.w, xv.z, acc[i].w);
            acc[i].x = fmaf(w3.x, xv.w, acc[i].x);
            acc[i].y = fmaf(w3.y, xv.w, acc[i].y);
            acc[i].z = fmaf(w3.z, xv.w, acc[i].z);
            acc[i].w = fmaf(w3.w, xv.w, acc[i].w);
        }
    }
#pragma unroll
    for (int i = 0; i < 8; ++i)
        ((float4*)(xw + ((size_t)dir * S_LEN + t0 + i) * 1024))[tid] = acc[i];
}

// ---------------- LSTM recurrence ----------------
// 32 blocks x 256 threads. blk -> (dir = blk>>4, b = blk&15). Wave w owns
// h-dims D0..D0+3 (D0 = 16b+4w) for ALL FOUR gates (16 rows). Lane (v =
// lane>>2, u = lane&3): gate u, cols [16v,16v+16). After an in-wave xor
// butterfly over v, the wave holds all 16 row-sums -> i/f/g/o gathered by
// shfl, c/h replicated in-lane, lane0 publishes 4 stamped {t+1,h} u64 to the
// IC ring. Every wave polls the full 256-dim ring itself (dims 4*lane..+3;
// the 12 other needed cols arrive via shfl from partner lanes). The loop has
// ZERO barriers and ZERO LDS state except the read-only weight slots --
// R4-R6 showed the barrier/combiner chain (~2000cy) was the bottleneck.
__global__ __launch_bounds__(256, 1) void lstm_rec(
    const float* __restrict__ whh_f, const float* __restrict__ whh_b,
    const float* __restrict__ xw, float* __restrict__ hs,
    unsigned long long* __restrict__ ring) {
    int blk = blockIdx.x;
    int dir = blk >> 4;
    int b = blk & 15;
    int tid = threadIdx.x;
    int w = tid >> 6;          // wave 0..3
    int lane = tid & 63;
    int v = lane >> 2;         // col-chunk: cols 16v..16v+15
    int u = lane & 3;          // gate 0..3 (i,f,g,o)
    int D0 = b * 16 + w * 4;   // this wave's 4 h-dims

    __shared__ __align__(16) float4 wl4[4096];   // 64 KB weight slots

    const float* whh = dir ? whh_b : whh_f;
    // stage: slot (w, j, i) lane (v,u) = Whh[u*256 + D0 + j][16v+4i .. +3]
#pragma unroll
    for (int j = 0; j < 4; ++j)
#pragma unroll
        for (int i = 0; i < 4; ++i)
            wl4[((w * 16 + j * 4 + i) << 6) + lane] =
                *(const float4*)(whh + (size_t)(u * 256 + D0 + j) * 256 + 16 * v + 4 * i);
    __syncthreads();   // only barrier in the kernel

    const float* xwd = xw + (size_t)dir * S_LEN * 1024;
    float* hsd = hs + (size_t)dir * S_LEN * 256;
    unsigned long long* ringd = ring + dir * 512;   // [slot(2)][dim(256)]

    float4 hc0 = make_float4(0.f, 0.f, 0.f, 0.f);   // cols 16v+0..3
    float4 hc1 = hc0, hc2 = hc0, hc3 = hc0;         // +4..7, +8..11, +12..15
    float c0 = 0.f, c1 = 0.f, c2 = 0.f, c3 = 0.f;   // replicated cell state
    float4 xwv = *(const float4*)(xwd + u * 256 + D0);  // rows (gate u, dims D0..D0+3)
    int base = lane & ~3;
    int pb = 4 * lane;         // polled dims: 4*lane .. +3 == 16v+4u .. +3

#define WSLOT(j, i) wl4[((w * 16 + (j)*4 + (i)) << 6) + lane]

    for (int t = 0; t < S_LEN; ++t) {
        // ---- matvec: 16 conflict-free b128 weight reads + 64 FMAs ----
        float4 q, a0, a1, a2, a3;
        q = WSLOT(0, 0);
        a0.x = q.x * hc0.x; a0.y = q.y * hc0.y; a0.z = q.z * hc0.z; a0.w = q.w * hc0.w;
        q = WSLOT(1, 0);
        a1.x = q.x * hc0.x; a1.y = q.y * hc0.y; a1.z = q.z * hc0.z; a1.w = q.w * hc0.w;
        q = WSLOT(2, 0);
        a2.x = q.x * hc0.x; a2.y = q.y * hc0.y; a2.z = q.z * hc0.z; a2.w = q.w * hc0.w;
        q = WSLOT(3, 0);
        a3.x = q.x * hc0.x; a3.y = q.y * hc0.y; a3.z = q.z * hc0.z; a3.w = q.w * hc0.w;

        q = WSLOT(0, 1);
        a0.x = fmaf(q.x, hc1.x, a0.x); a0.y = fmaf(q.y, hc1.y, a0.y);
        a0.z = fmaf(q.z, hc1.z, a0.z); a0.w = fmaf(q.w, hc1.w, a0.w);
        q = WSLOT(1, 1);
        a1.x = fmaf(q.x, hc1.x, a1.x); a1.y = fmaf(q.y, hc1.y, a1.y);
        a1.z = fmaf(q.z, hc1.z, a1.z); a1.w = fmaf(q.w, hc1.w, a1.w);
        q = WSLOT(2, 1);
        a2.x = fmaf(q.x, hc1.x, a2.x); a2.y = fmaf(q.y, hc1.y, a2.y);
        a2.z = fmaf(q.z, hc1.z, a2.z); a2.w = fmaf(q.w, hc1.w, a2.w);
        q = WSLOT(3, 1);
        a3.x = fmaf(q.x, hc1.x, a3.x); a3.y = fmaf(q.y, hc1.y, a3.y);
        a3.z = fmaf(q.z, hc1.z, a3.z); a3.w = fmaf(q.w, hc1.w, a3.w);

        q = WSLOT(0, 2);
        a0.x = fmaf(q.x, hc2.x, a0.x); a0.y = fmaf(q.y, hc2.y, a0.y);
        a0.z = fmaf(q.z, hc2.z, a0.z); a0.w = fmaf(q.w, hc2.w, a0.w);
        q = WSLOT(1, 2);
        a1.x = fmaf(q.x, hc2.x, a1.x); a1.y = fmaf(q.y, hc2.y, a1.y);
        a1.z = fmaf(q.z, hc2.z, a1.z); a1.w = fmaf(q.w, hc2.w, a1.w);
        q = WSLOT(2, 2);
        a2.x = fmaf(q.x, hc2.x, a2.x); a2.y = fmaf(q.y, hc2.y, a2.y);
        a2.z = fmaf(q.z, hc2.z, a2.z); a2.w = fmaf(q.w, hc2.w, a2.w);
        q = WSLOT(3, 2);
        a3.x = fmaf(q.x, hc2.x, a3.x); a3.y = fmaf(q.y, hc2.y, a3.y);
        a3.z = fmaf(q.z, hc2.z, a3.z); a3.w = fmaf(q.w, hc2.w, a3.w);

        q = WSLOT(0, 3);
        a0.x = fmaf(q.x, hc3.x, a0.x); a0.y = fmaf(q.y, hc3.y, a0.y);
        a0.z = fmaf(q.z, hc3.z, a0.z); a0.w = fmaf(q.w, hc3.w, a0.w);
        q = WSLOT(1, 3);
        a1.x = fmaf(q.x, hc3.x, a1.x); a1.y = fmaf(q.y, hc3.y, a1.y);
        a1.z = fmaf(q.z, hc3.z, a1.z); a1.w = fmaf(q.w, hc3.w, a1.w);
        q = WSLOT(2, 3);
        a2.x = fmaf(q.x, hc3.x, a2.x); a2.y = fmaf(q.y, hc3.y, a2.y);
        a2.z = fmaf(q.z, hc3.z, a2.z); a2.w = fmaf(q.w, hc3.w, a2.w);
        q = WSLOT(3, 3);
        a3.x = fmaf(q.x, hc3.x, a3.x); a3.y = fmaf(q.y, hc3.y, a3.y);
        a3.z = fmaf(q.z, hc3.z, a3.z); a3.w = fmaf(q.w, hc3.w, a3.w);

        float s0 = (a0.x + a0.y) + (a0.z + a0.w);
        float s1 = (a1.x + a1.y) + (a1.z + a1.w);
        float s2 = (a2.x + a2.y) + (a2.z + a2.w);
        float s3 = (a3.x + a3.y) + (a3.z + a3.w);

        // ---- butterfly over the 16 v-groups (keeps u) ----
#pragma unroll
        for (int off = 4; off < 64; off <<= 1) {
            s0 += __shfl_xor(s0, off, 64);
            s1 += __shfl_xor(s1, off, 64);
            s2 += __shfl_xor(s2, off, 64);
            s3 += __shfl_xor(s3, off, 64);
        }

        // ---- z, activation (all lanes; gate = u) ----
        float z0 = s0 + xwv.x, z1 = s1 + xwv.y, z2 = s2 + xwv.z, z3 = s3 + xwv.w;
        float e0, e1, e2, e3;
        if (u == 2) {
            e0 = tanhf(z0); e1 = tanhf(z1); e2 = tanhf(z2); e3 = tanhf(z3);
        } else {
            e0 = 1.f / (1.f + expf(-z0)); e1 = 1.f / (1.f + expf(-z1));
            e2 = 1.f / (1.f + expf(-z2)); e3 = 1.f / (1.f + expf(-z3));
        }

        // prefetch next xw (consumed next iteration, hidden under poll)
        int tn = (t + 1 < S_LEN) ? t + 1 : t;
        float4 xwn = *(const float4*)(xwd + (size_t)tn * 1024 + u * 256 + D0);

        // ---- gather i,f,g,o per dim; replicated c/h update ----
        float i0 = __shfl(e0, base + 0, 64), f0 = __shfl(e0, base + 1, 64);
        float g0 = __shfl(e0, base + 2, 64), o0 = __shfl(e0, base + 3, 64);
        float i1 = __shfl(e1, base + 0, 64), f1 = __shfl(e1, base + 1, 64);
        float g1 = __shfl(e1, base + 2, 64), o1 = __shfl(e1, base + 3, 64);
        float i2 = __shfl(e2, base + 0, 64), f2 = __shfl(e2, base + 1, 64);
        float g2 = __shfl(e2, base + 2, 64), o2 = __shfl(e2, base + 3, 64);
        float i3 = __shfl(e3, base + 0, 64), f3 = __shfl(e3, base + 1, 64);
        float g3 = __shfl(e3, base + 2, 64), o3 = __shfl(e3, base + 3, 64);
        c0 = fmaf(f0, c0, i0 * g0); float h0v = o0 * tanhf(c0);
        c1 = fmaf(f1, c1, i1 * g1); float h1v = o1 * tanhf(c1);
        c2 = fmaf(f2, c2, i2 * g2); float h2v = o2 * tanhf(c2);
        c3 = fmaf(f3, c3, i3 * g3); float h3v = o3 * tanhf(c3);

        // ---- publish (lane 0) ----
        unsigned long long* slot = ringd + (size_t)(t & 1) * 256;
        unsigned int want = (unsigned int)(t + 1);
        if (lane == 0) {
            *(float4*)(hsd + (size_t)t * 256 + D0) = make_float4(h0v, h1v, h2v, h3v);
            unsigned long long hw = ((unsigned long long)want << 32);
            __hip_atomic_store(&slot[D0 + 0], hw | __float_as_uint(h0v),
                               __ATOMIC_RELAXED, __HIP_MEMORY_SCOPE_AGENT);
            __hip_atomic_store(&slot[D0 + 1], hw | __float_as_uint(h1v),
                               __ATOMIC_RELAXED, __HIP_MEMORY_SCOPE_AGENT);
            __hip_atomic_store(&slot[D0 + 2], hw | __float_as_uint(h2v),
                               __ATOMIC_RELAXED, __HIP_MEMORY_SCOPE_AGENT);
            __hip_atomic_store(&slot[D0 + 3], hw | __float_as_uint(h3v),
                               __ATOMIC_RELAXED, __HIP_MEMORY_SCOPE_AGENT);
        }

        // ---- poll the full ring (dims 4*lane..+3) ----
        unsigned long long p0, p1, p2, p3;
        for (;;) {
            p0 = __hip_atomic_load(&slot[pb + 0], __ATOMIC_RELAXED, __HIP_MEMORY_SCOPE_AGENT);
            p1 = __hip_atomic_load(&slot[pb + 1], __ATOMIC_RELAXED, __HIP_MEMORY_SCOPE_AGENT);
            p2 = __hip_atomic_load(&slot[pb + 2], __ATOMIC_RELAXED, __HIP_MEMORY_SCOPE_AGENT);
            p3 = __hip_atomic_load(&slot[pb + 3], __ATOMIC_RELAXED, __HIP_MEMORY_SCOPE_AGENT);
            bool ok = ((unsigned int)(p0 >> 32) == want) &
                      ((unsigned int)(p1 >> 32) == want) &
                      ((unsigned int)(p2 >> 32) == want) &
                      ((unsigned int)(p3 >> 32) == want);
            if (__all(ok)) break;
        }
        float m0 = __uint_as_float((unsigned int)p0);
        float m1 = __uint_as_float((unsigned int)p1);
        float m2 = __uint_as_float((unsigned int)p2);
        float m3 = __uint_as_float((unsigned int)p3);

        // ---- redistribute: hc_i.k = h[16v+4i+k] = m_k of lane (v,i) ----
        hc0.x = __shfl(m0, base + 0, 64); hc0.y = __shfl(m1, base + 0, 64);
        hc0.z = __shfl(m2, base + 0, 64); hc0.w = __shfl(m3, base + 0, 64);
        hc1.x = __shfl(m0, base + 1, 64); hc1.y = __shfl(m1, base + 1, 64);
        hc1.z = __shfl(m2, base + 1, 64); hc1.w = __shfl(m3, base + 1, 64);
        hc2.x = __shfl(m0, base + 2, 64); hc2.y = __shfl(m1, base + 2, 64);
        hc2.z = __shfl(m2, base + 2, 64); hc2.w = __shfl(m3, base + 2, 64);
        hc3.x = __shfl(m0, base + 3, 64); hc3.y = __shfl(m1, base + 3, 64);
        hc3.z = __shfl(m2, base + 3, 64); hc3.w = __shfl(m3, base + 3, 64);
        xwv = xwn;
    }
#undef WSLOT
}

// ---------------- feats = [h_f, h_b] @ W_out^T + b_out ----------------
__global__ __launch_bounds__(64) void feats_k(const float* __restrict__ hs,
                                              const float* __restrict__ wout,
                                              const float* __restrict__ bout,
                                              float* __restrict__ feats) {
    int t = blockIdx.x, tau = blockIdx.y, lane = threadIdx.x;
    const float* hf = hs + (size_t)t * 256;
    const float* hbk = hs + (size_t)S_LEN * 256 + (size_t)(S_LEN - 1 - t) * 256;
    const float* w = wout + (size_t)tau * 512;
    float s = 0.f;
#pragma unroll
    for (int m = 0; m < 4; ++m) s = fmaf(w[lane + 64 * m], hf[lane + 64 * m], s);
#pragma unroll
    for (int m = 0; m < 4; ++m) s = fmaf(w[256 + lane + 64 * m], hbk[lane + 64 * m], s);
#pragma unroll
    for (int off = 32; off > 0; off >>= 1) s += __shfl_down(s, off, 64);
    if (lane == 0) feats[(size_t)t * NTAG + tau] = s + bout[tau];
}

// ---------------- Viterbi: single wave, shfl-broadcast ----------------
__global__ __launch_bounds__(64) void viterbi_k(const float* __restrict__ feats,
                                                const float* __restrict__ trans,
                                                float* __restrict__ out) {
    __shared__ float fstage[128 * NTAG];
    __shared__ unsigned char bp[S_LEN * NTAG];
    __shared__ float path[S_LEN];
    __shared__ float term[16];
    int tid = threadIdx.x;
    int rr = (tid < NTAG) ? tid : 0;
    float tr[NTAG];
#pragma unroll
    for (int j = 0; j < NTAG; ++j) tr[j] = trans[rr * NTAG + j];
    float trstop = trans[STOP_TAG * NTAG + rr];
    float fv = (tid == START_TAG) ? 0.f : NEGV;

    for (int t0 = 0; t0 < S_LEN; t0 += 128) {
        __syncthreads();
        for (int i = tid; i < 128 * NTAG; i += 64) fstage[i] = feats[(size_t)t0 * NTAG + i];
        __syncthreads();
        for (int tt = 0; tt < 128; ++tt) {
            float b0 = __shfl(fv, 0, 64), b1 = __shfl(fv, 1, 64);
            float b2 = __shfl(fv, 2, 64), b3 = __shfl(fv, 3, 64);
            float b4 = __shfl(fv, 4, 64), b5 = __shfl(fv, 5, 64);
            float b6 = __shfl(fv, 6, 64), b7 = __shfl(fv, 7, 64);
            float b8 = __shfl(fv, 8, 64), b9 = __shfl(fv, 9, 64);
            float best = b0 + tr[0]; int bj = 0;
            float vv;
            vv = b1 + tr[1]; if (vv > best) { best = vv; bj = 1; }
            vv = b2 + tr[2]; if (vv > best) { best = vv; bj = 2; }
            vv = b3 + tr[3]; if (vv > best) { best = vv; bj = 3; }
            vv = b4 + tr[4]; if (vv > best) { best = vv; bj = 4; }
            vv = b5 + tr[5]; if (vv > best) { best = vv; bj = 5; }
            vv = b6 + tr[6]; if (vv > best) { best = vv; bj = 6; }
            vv = b7 + tr[7]; if (vv > best) { best = vv; bj = 7; }
            vv = b8 + tr[8]; if (vv > best) { best = vv; bj = 8; }
            vv = b9 + tr[9]; if (vv > best) { best = vv; bj = 9; }
            if (tid < NTAG) {
                bp[(t0 + tt) * NTAG + tid] = (unsigned char)bj;
                fv = best + fstage[tt * NTAG + tid];
            }
        }
    }
    if (tid < NTAG) term[tid] = fv + trstop;
    __syncthreads();
    if (tid == 0) {
        float best = -3.4e38f; int bi = 0;
#pragma unroll
        for (int i = 0; i < NTAG; ++i) {
            float v = term[i];
            if (v > best) { best = v; bi = i; }
        }
        out[0] = best;
        int tag = bi;
        for (int t = S_LEN - 1; t >= 0; --t) {
            path[t] = (float)tag;
            tag = bp[t * NTAG + tag];
        }
    }
    __syncthreads();
    for (int i = tid; i < S_LEN; i += 64) out[1 + i] = path[i];
}

extern "C" void kernel_launch(void* const* d_in, const int* in_sizes, int n_in,
                              void* d_out, int out_size, void* d_ws, size_t ws_size,
                              hipStream_t stream) {
    const int* sent = (const int*)d_in[0];
    const float* emb = (const float*)d_in[1];
    const float* wih_f = (const float*)d_in[2];
    const float* whh_f = (const float*)d_in[3];
    const float* bih_f = (const float*)d_in[4];
    const float* bhh_f = (const float*)d_in[5];
    const float* wih_b = (const float*)d_in[6];
    const float* whh_b = (const float*)d_in[7];
    const float* bih_b = (const float*)d_in[8];
    const float* bhh_b = (const float*)d_in[9];
    const float* wout = (const float*)d_in[10];
    const float* bout = (const float*)d_in[11];
    const float* trans = (const float*)d_in[12];

    float* ws = (float*)d_ws;
    float* xw = ws + XW_OFF;
    float* hs = ws + HS_OFF;
    float* wT = ws + WT_OFF;
    float* fe = ws + FE_OFF;
    unsigned long long* ring = (unsigned long long*)(ws + RING_OFF);

    hipLaunchKernelGGL(transpose_wih, dim3(8, 32, 2), dim3(32, 32), 0, stream,
                       wih_f, wih_b, wT);
    hipLaunchKernelGGL(xw_gemm, dim3(S_LEN / 8, 2), dim3(256), 0, stream,
                       sent, emb, wT, bih_f, bhh_f, bih_b, bhh_b, xw);
    hipLaunchKernelGGL(lstm_rec, dim3(32), dim3(256), 0, stream,
                       whh_f, whh_b, xw, hs, ring);
    hipLaunchKernelGGL(feats_k, dim3(S_LEN, NTAG), dim3(64), 0, stream,
                       hs, wout, bout, fe);
    hipLaunchKernelGGL(viterbi_k, dim3(1), dim3(64), 0, stream,
                       fe, trans, (float*)d_out);
}